// Round 7
// baseline (435.235 us; speedup 1.0000x reference)
//
#include <hip/hip_runtime.h>
#include <hip/hip_bf16.h>
#include <math.h>

#define NH     4
#define RD     5
#define WW     49
#define DM     256
#define BATCH  32
#define NTOK   4900
#define GSEG   20
#define SEG    245            // WW*RD tokens per segment
#define XTB    (64 * 256)     // XT base offset in shorts

typedef short bf16x8 __attribute__((ext_vector_type(8)));
typedef short bf16x4 __attribute__((ext_vector_type(4)));
typedef float f32x4  __attribute__((ext_vector_type(4)));

__device__ __forceinline__ short f2bf(float f) {
    union { __hip_bfloat16 h; short s; } u;
    u.h = __float2bfloat16(f);
    return u.s;
}

__device__ __forceinline__ void gl_lds16(const void* g, void* l) {
    __builtin_amdgcn_global_load_lds(
        (const __attribute__((address_space(1))) void*)g,
        (__attribute__((address_space(3))) void*)l, 16, 0, 0);
}

// X tile: [64 tokens][256 d] bf16, pitch 256, XOR-swizzle on 8-short granules.
__device__ __forceinline__ int qix(int row, int col) {
    return row * 256 + (col ^ ((row & 7) << 3));
}
// XT tile: [256 d][64 j] bf16, pitch 64, 4-short-granule EVEN-mask swizzle
// (bit0 of granule untouched -> b128 reads stay in j-order).
__device__ __forceinline__ int tix4(int d, int j) {
    return XTB + d * 64 + ((((j >> 2) ^ ((d & 7) << 1)) << 2) | (j & 3));
}

// ---------------------------------------------------------------------------
// Pre-convert Wq, Wo (fp32 [256,256]) to bf16.
// ---------------------------------------------------------------------------
__global__ __launch_bounds__(256)
void wcvt(const float* __restrict__ Wq, const float* __restrict__ Wo,
          short* __restrict__ Wqb, short* __restrict__ Wob) {
    int t = blockIdx.x * 256 + threadIdx.x;       // 0..32767 float4 units
    const float* src = (t < 16384) ? Wq : Wo;
    short* dst = (t < 16384) ? Wqb : Wob;
    int i = (t & 16383) * 4;
    float4 v = *(const float4*)(src + i);
    bf16x4 o = { f2bf(v.x), f2bf(v.y), f2bf(v.z), f2bf(v.w) };
    *(bf16x4*)(dst + i) = o;
}

// ---------------------------------------------------------------------------
// Fused: one block per (b,g,r). 512 threads = 8 waves: wave = (hf, hd),
// hf = M-half (32 token rows), hd = head / 64-col N-slice.
//   Phase 0: stage 49 emb rows fp32 -> LDS (global_load_lds, 3-bit chunk swz)
//   Phase 1: X = bf16(emb @ Wq^T + bq); XT written vectorized (bf16x4)
//   Phase 2: attention; sa[j-grp][own-i] keeps softmax wave-complete
//   Phase 3: out = O @ Wo^T + bo
// LDS 64 KB -> 2 blocks/CU -> 16 waves/CU (4/SIMD). 5 __syncthreads.
// ---------------------------------------------------------------------------
__global__ __launch_bounds__(512, 4)
void fused(const float* __restrict__ emb, const short* __restrict__ Wqb,
           const float* __restrict__ bq, const short* __restrict__ Wob,
           const float* __restrict__ bo, float* __restrict__ out) {
    __shared__ __align__(16) short sm[XTB + 64 * 256];   // 64 KB: X | XT
    float* As = (float*)sm;                              // phase-1 alias

    const int tid = threadIdx.x;
    const int wv = tid >> 6, ln = tid & 63, lc = ln & 15, lq = ln >> 4;
    const int hd = wv & 3, hf = wv >> 2;
    const int wn = hd * 64, wm = hf * 32;

    const int bid = blockIdx.x;                   // 3200 = 32*20*5
    const int b = bid / 100;
    const int rem = bid - b * 100;
    const int g = rem / 5, r = rem - (rem / 5) * 5;
    const size_t tok0 = (size_t)b * NTOK + (size_t)g * SEG + r;

    // ============ Phase 0: async-stage emb rows 0..48 (fp32) =============
    for (int p = wv; p < WW; p += 8)
        gl_lds16(emb + (tok0 + (size_t)p * RD) * DM +
                     (size_t)((ln ^ (p & 7)) << 2),
                 (char*)sm + p * 1024);
    __syncthreads();   // drains vmcnt -> A-stage valid

    // ============ Phase 1: k-loop, A from LDS, weights depth-2 ============
    f32x4 acc[2][4] = {};
    {
        const short* br[4];
        #pragma unroll
        for (int ni = 0; ni < 4; ni++)
            br[ni] = Wqb + (size_t)(wn + ni * 16 + lc) * DM + lq * 8;
        bf16x8 wb[2][4];
        #pragma unroll
        for (int ni = 0; ni < 4; ni++) wb[0][ni] = *(const bf16x8*)(br[ni]);
        #pragma unroll
        for (int ni = 0; ni < 4; ni++) wb[1][ni] = *(const bf16x8*)(br[ni] + 32);

        #pragma unroll
        for (int ks = 0; ks < 8; ks++) {
            bf16x8 af[2];
            #pragma unroll
            for (int mi = 0; mi < 2; mi++) {
                const int t = wm + mi * 16 + lc;   // rows>=49: stale, masked later
                const int clo = (ks * 8 + lq * 2) ^ (t & 7);
                float4 lo = *(const float4*)&As[t * 256 + clo * 4];
                float4 hi = *(const float4*)&As[t * 256 + (clo ^ 1) * 4];
                af[mi] = (bf16x8){ f2bf(lo.x), f2bf(lo.y), f2bf(lo.z), f2bf(lo.w),
                                   f2bf(hi.x), f2bf(hi.y), f2bf(hi.z), f2bf(hi.w) };
            }
            #pragma unroll
            for (int mi = 0; mi < 2; mi++)
                #pragma unroll
                for (int ni = 0; ni < 4; ni++)
                    acc[mi][ni] = __builtin_amdgcn_mfma_f32_16x16x32_bf16(
                        af[mi], wb[ks & 1][ni], acc[mi][ni], 0, 0, 0);
            if (ks < 6) {
                #pragma unroll
                for (int ni = 0; ni < 4; ni++)
                    wb[ks & 1][ni] = *(const bf16x8*)(br[ni] + (ks + 2) * 32);
            }
        }
    }
    __syncthreads();   // A-stage dead everywhere -> X|XT region writable

    // ===== Phase-1 epilogue: X scalar, XT VECTOR (rg axis = token axis) ====
    {
        float bv[4];
        #pragma unroll
        for (int ni = 0; ni < 4; ni++) bv[ni] = bq[wn + ni * 16 + lc];
        #pragma unroll
        for (int mi = 0; mi < 2; mi++) {
            const int t0 = wm + mi * 16 + lq * 4;
            #pragma unroll
            for (int ni = 0; ni < 4; ni++) {
                const int col = wn + ni * 16 + lc;
                short s[4];
                #pragma unroll
                for (int rg = 0; rg < 4; rg++)
                    s[rg] = (t0 + rg < WW) ? f2bf(acc[mi][ni][rg] + bv[ni])
                                           : (short)0;
                #pragma unroll
                for (int rg = 0; rg < 4; rg++)
                    sm[qix(t0 + rg, col)] = s[rg];
                bf16x4 w = { s[0], s[1], s[2], s[3] };
                *(bf16x4*)&sm[tix4(col, t0)] = w;
            }
        }
    }
    __syncthreads();   // X/XT valid block-wide

    // ============ Phase 2: attention (head hd, own i-rows wm..wm+31) =======
    {
        const int c0 = wn;
        // A-frags: ALL 64 j rows; B-frags: own 32 i rows.
        bf16x8 xa[4][2], xb[2][2];
        #pragma unroll
        for (int mj = 0; mj < 4; mj++) {
            xa[mj][0] = *(const bf16x8*)&sm[qix(mj * 16 + lc, c0 + lq * 8)];
            xa[mj][1] = *(const bf16x8*)&sm[qix(mj * 16 + lc, c0 + 32 + lq * 8)];
        }
        #pragma unroll
        for (int ni = 0; ni < 2; ni++) {
            xb[ni][0] = *(const bf16x8*)&sm[qix(wm + ni * 16 + lc, c0 + lq * 8)];
            xb[ni][1] = *(const bf16x8*)&sm[qix(wm + ni * 16 + lc, c0 + 32 + lq * 8)];
        }
        // sa[mj][ni][rg] = S[j = 16mj+4lq+rg][i = wm+16ni+lc]
        f32x4 sa[4][2] = {};
        #pragma unroll
        for (int mj = 0; mj < 4; mj++)
            #pragma unroll
            for (int ni = 0; ni < 2; ni++) {
                sa[mj][ni] = __builtin_amdgcn_mfma_f32_16x16x32_bf16(
                    xa[mj][0], xb[ni][0], sa[mj][ni], 0, 0, 0);
                sa[mj][ni] = __builtin_amdgcn_mfma_f32_16x16x32_bf16(
                    xa[mj][1], xb[ni][1], sa[mj][ni], 0, 0, 0);
            }
        __syncthreads();   // all waves' X reads complete before P overwrites X

        // softmax over j for each own-i column; write P rows (bf16x4)
        const int jb = lq * 4;
        #pragma unroll
        for (int ni = 0; ni < 2; ni++) {
            float m = -1e30f;
            #pragma unroll
            for (int mj = 0; mj < 4; mj++)
                #pragma unroll
                for (int rg = 0; rg < 4; rg++) {
                    sa[mj][ni][rg] *= 0.125f;     // 1/sqrt(64)
                    if (16 * mj + jb + rg < WW) m = fmaxf(m, sa[mj][ni][rg]);
                }
            m = fmaxf(m, __shfl_xor(m, 16));
            m = fmaxf(m, __shfl_xor(m, 32));
            float l_ = 0.f;
            #pragma unroll
            for (int mj = 0; mj < 4; mj++)
                #pragma unroll
                for (int rg = 0; rg < 4; rg++) {
                    const float e = (16 * mj + jb + rg < WW)
                                        ? __expf(sa[mj][ni][rg] - m) : 0.f;
                    sa[mj][ni][rg] = e;
                    l_ += e;
                }
            l_ += __shfl_xor(l_, 16);
            l_ += __shfl_xor(l_, 32);
            const float inv = 1.f / l_;
            const int i = wm + ni * 16 + lc;      // own P row (query token)
            #pragma unroll
            for (int mj = 0; mj < 4; mj++) {
                bf16x4 pw = { f2bf(sa[mj][ni][0] * inv), f2bf(sa[mj][ni][1] * inv),
                              f2bf(sa[mj][ni][2] * inv), f2bf(sa[mj][ni][3] * inv) };
                *(bf16x4*)&sm[qix(i, c0 + 16 * mj + jb)] = pw;
            }
        }
        // O = P · X   (A: own P rows; B: XT via tix4 — both j-ordered)
        bf16x8 pa[2][2], pb[4][2];
        #pragma unroll
        for (int ni = 0; ni < 2; ni++) {
            pa[ni][0] = *(const bf16x8*)&sm[qix(wm + ni * 16 + lc, c0 + lq * 8)];
            pa[ni][1] = *(const bf16x8*)&sm[qix(wm + ni * 16 + lc, c0 + 32 + lq * 8)];
        }
        #pragma unroll
        for (int nd = 0; nd < 4; nd++) {
            pb[nd][0] = *(const bf16x8*)&sm[tix4(c0 + nd * 16 + lc, lq * 8)];
            pb[nd][1] = *(const bf16x8*)&sm[tix4(c0 + nd * 16 + lc, 32 + lq * 8)];
        }
        f32x4 oa[2][4] = {};
        #pragma unroll
        for (int ni = 0; ni < 2; ni++)
            #pragma unroll
            for (int nd = 0; nd < 4; nd++) {
                oa[ni][nd] = __builtin_amdgcn_mfma_f32_16x16x32_bf16(
                    pa[ni][0], pb[nd][0], oa[ni][nd], 0, 0, 0);
                oa[ni][nd] = __builtin_amdgcn_mfma_f32_16x16x32_bf16(
                    pa[ni][1], pb[nd][1], oa[ni][nd], 0, 0, 0);
            }
        // O overwrites P in X[:, c0:c0+64), own rows < 49 only.
        #pragma unroll
        for (int ni = 0; ni < 2; ni++)
            #pragma unroll
            for (int rg = 0; rg < 4; rg++) {
                const int i = wm + ni * 16 + lq * 4 + rg;
                if (i < WW) {
                    #pragma unroll
                    for (int nd = 0; nd < 4; nd++)
                        sm[qix(i, c0 + nd * 16 + lc)] = f2bf(oa[ni][nd][rg]);
                }
            }
    }
    __syncthreads();

    // ============ Phase 3: out = O @ Wo^T + bo (weights depth-2) ==========
    {
        const short* br[4];
        #pragma unroll
        for (int ni = 0; ni < 4; ni++)
            br[ni] = Wob + (size_t)(wn + ni * 16 + lc) * DM + lq * 8;
        int trow[2];
        #pragma unroll
        for (int mi = 0; mi < 2; mi++) {
            int t = wm + mi * 16 + lc;
            trow[mi] = (t > WW - 1) ? (WW - 1) : t;   // avoid stale pad rows
        }
        f32x4 ac3[2][4] = {};
        bf16x8 wb[2][4];
        #pragma unroll
        for (int ni = 0; ni < 4; ni++) wb[0][ni] = *(const bf16x8*)(br[ni]);
        #pragma unroll
        for (int ni = 0; ni < 4; ni++) wb[1][ni] = *(const bf16x8*)(br[ni] + 32);

        #pragma unroll
        for (int ks = 0; ks < 8; ks++) {
            bf16x8 af[2];
            #pragma unroll
            for (int mi = 0; mi < 2; mi++)
                af[mi] = *(const bf16x8*)&sm[qix(trow[mi], ks * 32 + lq * 8)];
            #pragma unroll
            for (int mi = 0; mi < 2; mi++)
                #pragma unroll
                for (int ni = 0; ni < 4; ni++)
                    ac3[mi][ni] = __builtin_amdgcn_mfma_f32_16x16x32_bf16(
                        af[mi], wb[ks & 1][ni], ac3[mi][ni], 0, 0, 0);
            if (ks < 6) {
                #pragma unroll
                for (int ni = 0; ni < 4; ni++)
                    wb[ks & 1][ni] = *(const bf16x8*)(br[ni] + (ks + 2) * 32);
            }
        }
        float bv[4];
        #pragma unroll
        for (int ni = 0; ni < 4; ni++) bv[ni] = bo[wn + ni * 16 + lc];
        #pragma unroll
        for (int mi = 0; mi < 2; mi++)
            #pragma unroll
            for (int rg = 0; rg < 4; rg++) {
                const int t = wm + mi * 16 + lq * 4 + rg;
                if (t < WW) {
                    float* op = out + (tok0 + (size_t)t * RD) * DM + wn;
                    #pragma unroll
                    for (int ni = 0; ni < 4; ni++)
                        op[ni * 16 + lc] = ac3[mi][ni][rg] + bv[ni];
                }
            }
    }
}

// ---------------------------------------------------------------------------
extern "C" void kernel_launch(void* const* d_in, const int* in_sizes, int n_in,
                              void* d_out, int out_size, void* d_ws, size_t ws_size,
                              hipStream_t stream) {
    const float* emb = (const float*)d_in[0];
    const float* Wq  = (const float*)d_in[1];
    const float* bq  = (const float*)d_in[2];
    const float* Wo  = (const float*)d_in[3];
    const float* bo  = (const float*)d_in[4];
    float* out = (float*)d_out;

    // Workspace: Wq bf16 (128 KB) | Wo bf16 (128 KB)
    short* Wqb = (short*)d_ws;
    short* Wob = Wqb + DM * DM;

    wcvt<<<dim3(128), dim3(256), 0, stream>>>(Wq, Wo, Wqb, Wob);
    fused<<<dim3(BATCH * GSEG * RD), dim3(512), 0, stream>>>(
        emb, Wqb, bq, Wob, bo, out);
}

// Round 8
// 434.970 us; speedup vs baseline: 1.0006x; 1.0006x over previous
//
#include <hip/hip_runtime.h>
#include <hip/hip_bf16.h>
#include <math.h>

#define NH     4
#define RD     5
#define WW     49
#define DM     256
#define BATCH  32
#define NTOK   4900
#define GSEG   20
#define SEG    245            // WW*RD tokens per segment
#define XTB    (64 * 256)     // XT base offset in shorts

typedef short bf16x8 __attribute__((ext_vector_type(8)));
typedef short bf16x4 __attribute__((ext_vector_type(4)));
typedef float f32x4  __attribute__((ext_vector_type(4)));

__device__ __forceinline__ short f2bf(float f) {
    union { __hip_bfloat16 h; short s; } u;
    u.h = __float2bfloat16(f);
    return u.s;
}

__device__ __forceinline__ void gl_lds16(const void* g, void* l) {
    __builtin_amdgcn_global_load_lds(
        (const __attribute__((address_space(1))) void*)g,
        (__attribute__((address_space(3))) void*)l, 16, 0, 0);
}

// X tile: [64 tokens][256 d] bf16, pitch 256, XOR-swizzle on 8-short granules.
__device__ __forceinline__ int qix(int row, int col) {
    return row * 256 + (col ^ ((row & 7) << 3));
}
// XT tile: [256 d][64 j] bf16, pitch 64, 4-short-granule EVEN-mask swizzle
// (bit0 of granule untouched -> b128 reads stay in j-order).
__device__ __forceinline__ int tix4(int d, int j) {
    return XTB + d * 64 + ((((j >> 2) ^ ((d & 7) << 1)) << 2) | (j & 3));
}

// ---------------------------------------------------------------------------
// Pre-convert Wq, Wo (fp32 [256,256]) to bf16.
// ---------------------------------------------------------------------------
__global__ __launch_bounds__(256)
void wcvt(const float* __restrict__ Wq, const float* __restrict__ Wo,
          short* __restrict__ Wqb, short* __restrict__ Wob) {
    int t = blockIdx.x * 256 + threadIdx.x;       // 0..32767 float4 units
    const float* src = (t < 16384) ? Wq : Wo;
    short* dst = (t < 16384) ? Wqb : Wob;
    int i = (t & 16383) * 4;
    float4 v = *(const float4*)(src + i);
    bf16x4 o = { f2bf(v.x), f2bf(v.y), f2bf(v.z), f2bf(v.w) };
    *(bf16x4*)(dst + i) = o;
}

// ---------------------------------------------------------------------------
// Fused: one block per (b,g,r). 512 threads = 8 waves: wave = (hf, hd),
// hf = M-half (32 token rows), hd = head / 64-col N-slice.
//   Phase 0: stage 49 emb rows fp32 -> LDS (global_load_lds, 3-bit chunk swz)
//   Phase 1: X = bf16(emb @ Wq^T + bq); XT written vectorized (bf16x4)
//   Phase 2: attention; sa[j-grp][own-i] keeps softmax wave-complete
//   Phase 3: out = O @ Wo^T + bo
// LDS 64 KB -> 2 blocks/CU. __launch_bounds__(512,2): VGPR cap 256 so the
// allocator is NOT squeezed (R3/R7 showed (512,4) forces 64 VGPR and loses);
// expected ~112 VGPR <= 128 -> HW runs 4 waves/SIMD anyway.
// ---------------------------------------------------------------------------
__global__ __launch_bounds__(512, 2)
void fused(const float* __restrict__ emb, const short* __restrict__ Wqb,
           const float* __restrict__ bq, const short* __restrict__ Wob,
           const float* __restrict__ bo, float* __restrict__ out) {
    __shared__ __align__(16) short sm[XTB + 64 * 256];   // 64 KB: X | XT
    float* As = (float*)sm;                              // phase-1 alias

    const int tid = threadIdx.x;
    const int wv = tid >> 6, ln = tid & 63, lc = ln & 15, lq = ln >> 4;
    const int hd = wv & 3, hf = wv >> 2;
    const int wn = hd * 64, wm = hf * 32;

    const int bid = blockIdx.x;                   // 3200 = 32*20*5
    const int b = bid / 100;
    const int rem = bid - b * 100;
    const int g = rem / 5, r = rem - (rem / 5) * 5;
    const size_t tok0 = (size_t)b * NTOK + (size_t)g * SEG + r;

    // ============ Phase 0: async-stage emb rows 0..48 (fp32) =============
    for (int p = wv; p < WW; p += 8)
        gl_lds16(emb + (tok0 + (size_t)p * RD) * DM +
                     (size_t)((ln ^ (p & 7)) << 2),
                 (char*)sm + p * 1024);
    __syncthreads();   // drains vmcnt -> A-stage valid

    // ============ Phase 1: k-loop, A from LDS, weights depth-2 ============
    f32x4 acc[2][4] = {};
    {
        const short* br[4];
        #pragma unroll
        for (int ni = 0; ni < 4; ni++)
            br[ni] = Wqb + (size_t)(wn + ni * 16 + lc) * DM + lq * 8;
        bf16x8 wb[2][4];
        #pragma unroll
        for (int ni = 0; ni < 4; ni++) wb[0][ni] = *(const bf16x8*)(br[ni]);
        #pragma unroll
        for (int ni = 0; ni < 4; ni++) wb[1][ni] = *(const bf16x8*)(br[ni] + 32);

        #pragma unroll
        for (int ks = 0; ks < 8; ks++) {
            bf16x8 af[2];
            #pragma unroll
            for (int mi = 0; mi < 2; mi++) {
                const int t = wm + mi * 16 + lc;   // rows>=49: stale, masked later
                const int clo = (ks * 8 + lq * 2) ^ (t & 7);
                float4 lo = *(const float4*)&As[t * 256 + clo * 4];
                float4 hi = *(const float4*)&As[t * 256 + (clo ^ 1) * 4];
                af[mi] = (bf16x8){ f2bf(lo.x), f2bf(lo.y), f2bf(lo.z), f2bf(lo.w),
                                   f2bf(hi.x), f2bf(hi.y), f2bf(hi.z), f2bf(hi.w) };
            }
            #pragma unroll
            for (int mi = 0; mi < 2; mi++)
                #pragma unroll
                for (int ni = 0; ni < 4; ni++)
                    acc[mi][ni] = __builtin_amdgcn_mfma_f32_16x16x32_bf16(
                        af[mi], wb[ks & 1][ni], acc[mi][ni], 0, 0, 0);
            if (ks < 6) {
                #pragma unroll
                for (int ni = 0; ni < 4; ni++)
                    wb[ks & 1][ni] = *(const bf16x8*)(br[ni] + (ks + 2) * 32);
            }
        }
    }
    __syncthreads();   // A-stage dead everywhere -> X|XT region writable

    // ===== Phase-1 epilogue: X scalar, XT VECTOR (rg axis = token axis) ====
    {
        float bv[4];
        #pragma unroll
        for (int ni = 0; ni < 4; ni++) bv[ni] = bq[wn + ni * 16 + lc];
        #pragma unroll
        for (int mi = 0; mi < 2; mi++) {
            const int t0 = wm + mi * 16 + lq * 4;
            #pragma unroll
            for (int ni = 0; ni < 4; ni++) {
                const int col = wn + ni * 16 + lc;
                short s[4];
                #pragma unroll
                for (int rg = 0; rg < 4; rg++)
                    s[rg] = (t0 + rg < WW) ? f2bf(acc[mi][ni][rg] + bv[ni])
                                           : (short)0;
                #pragma unroll
                for (int rg = 0; rg < 4; rg++)
                    sm[qix(t0 + rg, col)] = s[rg];
                bf16x4 w = { s[0], s[1], s[2], s[3] };
                *(bf16x4*)&sm[tix4(col, t0)] = w;
            }
        }
    }
    __syncthreads();   // X/XT valid block-wide

    // ============ Phase 2: attention (head hd, own i-rows wm..wm+31) =======
    {
        const int c0 = wn;
        // A-frags: ALL 64 j rows; B-frags: own 32 i rows.
        bf16x8 xa[4][2], xb[2][2];
        #pragma unroll
        for (int mj = 0; mj < 4; mj++) {
            xa[mj][0] = *(const bf16x8*)&sm[qix(mj * 16 + lc, c0 + lq * 8)];
            xa[mj][1] = *(const bf16x8*)&sm[qix(mj * 16 + lc, c0 + 32 + lq * 8)];
        }
        #pragma unroll
        for (int ni = 0; ni < 2; ni++) {
            xb[ni][0] = *(const bf16x8*)&sm[qix(wm + ni * 16 + lc, c0 + lq * 8)];
            xb[ni][1] = *(const bf16x8*)&sm[qix(wm + ni * 16 + lc, c0 + 32 + lq * 8)];
        }
        // sa[mj][ni][rg] = S[j = 16mj+4lq+rg][i = wm+16ni+lc]
        f32x4 sa[4][2] = {};
        #pragma unroll
        for (int mj = 0; mj < 4; mj++)
            #pragma unroll
            for (int ni = 0; ni < 2; ni++) {
                sa[mj][ni] = __builtin_amdgcn_mfma_f32_16x16x32_bf16(
                    xa[mj][0], xb[ni][0], sa[mj][ni], 0, 0, 0);
                sa[mj][ni] = __builtin_amdgcn_mfma_f32_16x16x32_bf16(
                    xa[mj][1], xb[ni][1], sa[mj][ni], 0, 0, 0);
            }
        __syncthreads();   // all waves' X reads complete before P overwrites X

        // softmax over j for each own-i column; write P rows (bf16x4)
        const int jb = lq * 4;
        #pragma unroll
        for (int ni = 0; ni < 2; ni++) {
            float m = -1e30f;
            #pragma unroll
            for (int mj = 0; mj < 4; mj++)
                #pragma unroll
                for (int rg = 0; rg < 4; rg++) {
                    sa[mj][ni][rg] *= 0.125f;     // 1/sqrt(64)
                    if (16 * mj + jb + rg < WW) m = fmaxf(m, sa[mj][ni][rg]);
                }
            m = fmaxf(m, __shfl_xor(m, 16));
            m = fmaxf(m, __shfl_xor(m, 32));
            float l_ = 0.f;
            #pragma unroll
            for (int mj = 0; mj < 4; mj++)
                #pragma unroll
                for (int rg = 0; rg < 4; rg++) {
                    const float e = (16 * mj + jb + rg < WW)
                                        ? __expf(sa[mj][ni][rg] - m) : 0.f;
                    sa[mj][ni][rg] = e;
                    l_ += e;
                }
            l_ += __shfl_xor(l_, 16);
            l_ += __shfl_xor(l_, 32);
            const float inv = 1.f / l_;
            const int i = wm + ni * 16 + lc;      // own P row (query token)
            #pragma unroll
            for (int mj = 0; mj < 4; mj++) {
                bf16x4 pw = { f2bf(sa[mj][ni][0] * inv), f2bf(sa[mj][ni][1] * inv),
                              f2bf(sa[mj][ni][2] * inv), f2bf(sa[mj][ni][3] * inv) };
                *(bf16x4*)&sm[qix(i, c0 + 16 * mj + jb)] = pw;
            }
        }
        // O = P · X   (A: own P rows; B: XT via tix4 — both j-ordered)
        bf16x8 pa[2][2], pb[4][2];
        #pragma unroll
        for (int ni = 0; ni < 2; ni++) {
            pa[ni][0] = *(const bf16x8*)&sm[qix(wm + ni * 16 + lc, c0 + lq * 8)];
            pa[ni][1] = *(const bf16x8*)&sm[qix(wm + ni * 16 + lc, c0 + 32 + lq * 8)];
        }
        #pragma unroll
        for (int nd = 0; nd < 4; nd++) {
            pb[nd][0] = *(const bf16x8*)&sm[tix4(c0 + nd * 16 + lc, lq * 8)];
            pb[nd][1] = *(const bf16x8*)&sm[tix4(c0 + nd * 16 + lc, 32 + lq * 8)];
        }
        f32x4 oa[2][4] = {};
        #pragma unroll
        for (int ni = 0; ni < 2; ni++)
            #pragma unroll
            for (int nd = 0; nd < 4; nd++) {
                oa[ni][nd] = __builtin_amdgcn_mfma_f32_16x16x32_bf16(
                    pa[ni][0], pb[nd][0], oa[ni][nd], 0, 0, 0);
                oa[ni][nd] = __builtin_amdgcn_mfma_f32_16x16x32_bf16(
                    pa[ni][1], pb[nd][1], oa[ni][nd], 0, 0, 0);
            }
        // O overwrites P in X[:, c0:c0+64), own rows < 49 only.
        #pragma unroll
        for (int ni = 0; ni < 2; ni++)
            #pragma unroll
            for (int rg = 0; rg < 4; rg++) {
                const int i = wm + ni * 16 + lq * 4 + rg;
                if (i < WW) {
                    #pragma unroll
                    for (int nd = 0; nd < 4; nd++)
                        sm[qix(i, c0 + nd * 16 + lc)] = f2bf(oa[ni][nd][rg]);
                }
            }
    }
    __syncthreads();

    // ============ Phase 3: out = O @ Wo^T + bo (weights depth-2) ==========
    {
        const short* br[4];
        #pragma unroll
        for (int ni = 0; ni < 4; ni++)
            br[ni] = Wob + (size_t)(wn + ni * 16 + lc) * DM + lq * 8;
        int trow[2];
        #pragma unroll
        for (int mi = 0; mi < 2; mi++) {
            int t = wm + mi * 16 + lc;
            trow[mi] = (t > WW - 1) ? (WW - 1) : t;   // avoid stale pad rows
        }
        f32x4 ac3[2][4] = {};
        bf16x8 wb[2][4];
        #pragma unroll
        for (int ni = 0; ni < 4; ni++) wb[0][ni] = *(const bf16x8*)(br[ni]);
        #pragma unroll
        for (int ni = 0; ni < 4; ni++) wb[1][ni] = *(const bf16x8*)(br[ni] + 32);

        #pragma unroll
        for (int ks = 0; ks < 8; ks++) {
            bf16x8 af[2];
            #pragma unroll
            for (int mi = 0; mi < 2; mi++)
                af[mi] = *(const bf16x8*)&sm[qix(trow[mi], ks * 32 + lq * 8)];
            #pragma unroll
            for (int mi = 0; mi < 2; mi++)
                #pragma unroll
                for (int ni = 0; ni < 4; ni++)
                    ac3[mi][ni] = __builtin_amdgcn_mfma_f32_16x16x32_bf16(
                        af[mi], wb[ks & 1][ni], ac3[mi][ni], 0, 0, 0);
            if (ks < 6) {
                #pragma unroll
                for (int ni = 0; ni < 4; ni++)
                    wb[ks & 1][ni] = *(const bf16x8*)(br[ni] + (ks + 2) * 32);
            }
        }
        float bv[4];
        #pragma unroll
        for (int ni = 0; ni < 4; ni++) bv[ni] = bo[wn + ni * 16 + lc];
        #pragma unroll
        for (int mi = 0; mi < 2; mi++)
            #pragma unroll
            for (int rg = 0; rg < 4; rg++) {
                const int t = wm + mi * 16 + lq * 4 + rg;
                if (t < WW) {
                    float* op = out + (tok0 + (size_t)t * RD) * DM + wn;
                    #pragma unroll
                    for (int ni = 0; ni < 4; ni++)
                        op[ni * 16 + lc] = ac3[mi][ni][rg] + bv[ni];
                }
            }
    }
}

// ---------------------------------------------------------------------------
extern "C" void kernel_launch(void* const* d_in, const int* in_sizes, int n_in,
                              void* d_out, int out_size, void* d_ws, size_t ws_size,
                              hipStream_t stream) {
    const float* emb = (const float*)d_in[0];
    const float* Wq  = (const float*)d_in[1];
    const float* bq  = (const float*)d_in[2];
    const float* Wo  = (const float*)d_in[3];
    const float* bo  = (const float*)d_in[4];
    float* out = (float*)d_out;

    // Workspace: Wq bf16 (128 KB) | Wo bf16 (128 KB)
    short* Wqb = (short*)d_ws;
    short* Wob = Wqb + DM * DM;

    wcvt<<<dim3(128), dim3(256), 0, stream>>>(Wq, Wo, Wqb, Wob);
    fused<<<dim3(BATCH * GSEG * RD), dim3(512), 0, stream>>>(
        emb, Wqb, bq, Wob, bo, out);
}